// Round 1
// baseline (468.340 us; speedup 1.0000x reference)
//
#include <hip/hip_runtime.h>
#include <hip/hip_bf16.h>

#define NN 50000
#define NE 800000
#define NT_E 12500   // 800000 / 64

typedef __attribute__((ext_vector_type(8))) short bf16x8;   // 8 bf16 (4 VGPRs)
typedef __attribute__((ext_vector_type(4))) float f32x4;
typedef __attribute__((ext_vector_type(8))) unsigned short u16x8;

__device__ __forceinline__ unsigned short f2bf(float f) {
    union { float f; unsigned u; } v; v.f = f;
    unsigned r = v.u + 0x7FFFu + ((v.u >> 16) & 1u);   // RNE
    return (unsigned short)(r >> 16);
}
__device__ __forceinline__ float bf2f(unsigned short h) {
    union { unsigned u; float f; } v; v.u = ((unsigned)h) << 16;
    return v.f;
}
__device__ __forceinline__ f32x4 mfma16(bf16x8 a, bf16x8 b, f32x4 c) {
    return __builtin_amdgcn_mfma_f32_16x16x32_bf16(a, b, c, 0, 0, 0);
}

// ---- weight fragment loader: B[k][n] = W[n][k]; lane holds W[nt*16+(l&15)][kk*32+8*(l>>4)..+7]
__device__ __forceinline__ void load_wfrags(const unsigned short* __restrict__ Wb,
                                            int wv, int lane, bf16x8 (&wf)[4][2]) {
#pragma unroll
    for (int kk = 0; kk < 4; ++kk)
#pragma unroll
        for (int j = 0; j < 2; ++j) {
            int row = 32 * wv + 16 * j + (lane & 15);
            int col = 32 * kk + 8 * (lane >> 4);
            wf[kk][j] = *(const bf16x8*)(Wb + row * 128 + col);
        }
}

__device__ __forceinline__ void zero_acc(f32x4 (&acc)[4][2]) {
#pragma unroll
    for (int mt = 0; mt < 4; ++mt)
#pragma unroll
        for (int j = 0; j < 2; ++j) {
            f32x4 z = {0.f, 0.f, 0.f, 0.f};
            acc[mt][j] = z;
        }
}

// ---- GEMM: out[64][cols of this wave] += X[64][128] * W^T ; X padded [64][136]
__device__ __forceinline__ void gemm64(const unsigned short* __restrict__ X,
                                       const bf16x8 (&wf)[4][2], f32x4 (&acc)[4][2], int lane) {
#pragma unroll
    for (int kk = 0; kk < 4; ++kk) {
        bf16x8 a[4];
#pragma unroll
        for (int mt = 0; mt < 4; ++mt) {
            int row = mt * 16 + (lane & 15);
            a[mt] = *(const bf16x8*)(X + row * 136 + kk * 32 + 8 * (lane >> 4));
        }
#pragma unroll
        for (int mt = 0; mt < 4; ++mt) {
            acc[mt][0] = mfma16(a[mt], wf[kk][0], acc[mt][0]);
            acc[mt][1] = mfma16(a[mt], wf[kk][1], acc[mt][1]);
        }
    }
}

// ---- epilogue: relu(acc+bias) -> bf16 LDS tile
__device__ __forceinline__ void epi_lds(unsigned short* __restrict__ Xo,
                                        const f32x4 (&acc)[4][2],
                                        float bb0, float bb1, int c0, int rbase) {
#pragma unroll
    for (int mt = 0; mt < 4; ++mt)
#pragma unroll
        for (int r = 0; r < 4; ++r) {
            int row = mt * 16 + rbase + r;
            Xo[row * 136 + c0]      = f2bf(fmaxf(acc[mt][0][r] + bb0, 0.f));
            Xo[row * 136 + c0 + 16] = f2bf(fmaxf(acc[mt][1][r] + bb1, 0.f));
        }
}

// ================= kernel 1: convert 9 DxD fp32 weights to bf16 =================
__global__ void k_wconv(const float* w0, const float* w1, const float* w2,
                        const float* w3, const float* w4, const float* w5,
                        const float* w6, const float* w7, const float* w8,
                        unsigned short* out) {
    const float* ws[9] = {w0, w1, w2, w3, w4, w5, w6, w7, w8};
    int m = blockIdx.x >> 2;
    int part = blockIdx.x & 3;
    const float* w = ws[m] + part * 4096 + threadIdx.x * 16;
    unsigned short* o = out + m * 16384 + part * 4096 + threadIdx.x * 16;
    float f[16];
#pragma unroll
    for (int i = 0; i < 4; ++i) *(f32x4*)(f + 4 * i) = ((const f32x4*)w)[i];
    unsigned short tmp[16];
#pragma unroll
    for (int i = 0; i < 16; ++i) tmp[i] = f2bf(f[i]);
    ((u16x8*)o)[0] = *(u16x8*)tmp;
    ((u16x8*)o)[1] = *(u16x8*)(tmp + 8);
}

// ================= kernel 2: node pre: A_src, A_dst, Hb(bf16 h) =================
__global__ __launch_bounds__(256, 2)
void k_nodepre(const float* __restrict__ h,
               const unsigned short* __restrict__ Wb,
               const float* __restrict__ bsrc, const float* __restrict__ bdst,
               unsigned short* __restrict__ Asrc, unsigned short* __restrict__ Adst,
               unsigned short* __restrict__ Hb) {
    __shared__ unsigned short X[64 * 136];
    int tid = threadIdx.x, lane = tid & 63, wv = tid >> 6;
    int n0 = blockIdx.x * 64;
    {
        int row = tid >> 2, q = tid & 3;
        int n = n0 + row;
        unsigned short tmp[32];
        if (n < NN) {
            const f32x4* hp = (const f32x4*)(h + (size_t)n * 128 + q * 32);
#pragma unroll
            for (int i = 0; i < 8; ++i) {
                f32x4 v = hp[i];
#pragma unroll
                for (int j = 0; j < 4; ++j) tmp[i * 4 + j] = f2bf(v[j]);
            }
        } else {
#pragma unroll
            for (int i = 0; i < 32; ++i) tmp[i] = 0;
        }
#pragma unroll
        for (int i = 0; i < 4; ++i)
            *(u16x8*)(X + row * 136 + q * 32 + i * 8) = *(u16x8*)(tmp + i * 8);
        if (n < NN) {
            u16x8* hb = (u16x8*)(Hb + (size_t)n * 128 + q * 32);
#pragma unroll
            for (int i = 0; i < 4; ++i) hb[i] = *(u16x8*)(tmp + i * 8);
        }
    }
    __syncthreads();

    bf16x8 wfS[4][2], wfD[4][2];
    load_wfrags(Wb, wv, lane, wfS);            // Wsrc
    load_wfrags(Wb + 16384, wv, lane, wfD);    // Wdst
    f32x4 accS[4][2], accD[4][2];
    zero_acc(accS); zero_acc(accD);
    gemm64(X, wfS, accS, lane);
    gemm64(X, wfD, accD, lane);

    int c0 = 32 * wv + (lane & 15);
    float bs0 = bsrc[c0], bs1 = bsrc[c0 + 16];
    float bd0 = bdst[c0], bd1 = bdst[c0 + 16];
    int rbase = (lane >> 4) * 4;
#pragma unroll
    for (int mt = 0; mt < 4; ++mt)
#pragma unroll
        for (int r = 0; r < 4; ++r) {
            int n = n0 + mt * 16 + rbase + r;
            if (n < NN) {
                size_t o = (size_t)n * 128;
                Asrc[o + c0]      = f2bf(accS[mt][0][r] + bs0);
                Asrc[o + c0 + 16] = f2bf(accS[mt][1][r] + bs1);
                Adst[o + c0]      = f2bf(accD[mt][0][r] + bd0);
                Adst[o + c0 + 16] = f2bf(accD[mt][1][r] + bd1);
            }
        }
}

// ================= kernel 3: edge MLP + scatter-add =================
__global__ __launch_bounds__(256, 2)
void k_edge(const float* __restrict__ ef,
            const int* __restrict__ src, const int* __restrict__ dst,
            const unsigned short* __restrict__ Asrc,
            const unsigned short* __restrict__ Adst,
            const unsigned short* __restrict__ Hb,
            const unsigned short* __restrict__ Wb,
            const float* __restrict__ b1, const float* __restrict__ b2,
            const float* __restrict__ b3,
            float* __restrict__ agg) {
    __shared__ unsigned short X0[64 * 136];
    __shared__ unsigned short X1[64 * 136];
    __shared__ unsigned short Hs[64 * 136];
    __shared__ int soff_lds[64];
    __shared__ int doff_lds[64];

    int tid = threadIdx.x, lane = tid & 63, wv = tid >> 6;

    bf16x8 wf1[4][2], wf2[4][2], wf3[4][2];
    load_wfrags(Wb + 2 * 16384, wv, lane, wf1);   // Wphi1
    load_wfrags(Wb + 3 * 16384, wv, lane, wf2);   // Wphi2
    load_wfrags(Wb + 4 * 16384, wv, lane, wf3);   // Wphi3

    int c0 = 32 * wv + (lane & 15);
    float b1_0 = b1[c0], b1_1 = b1[c0 + 16];
    float b2_0 = b2[c0], b2_1 = b2[c0 + 16];
    float b3_0 = b3[c0], b3_1 = b3[c0 + 16];
    int rbase = (lane >> 4) * 4;
    int srow = tid >> 2, q = tid & 3;

    for (int t = blockIdx.x; t < NT_E; t += gridDim.x) {
        int e0 = t * 64;
        __syncthreads();                       // prev tile fully consumed
        if (tid < 64) {
            soff_lds[tid] = src[e0 + tid] * 128;
            doff_lds[tid] = dst[e0 + tid] * 128;
        }
        __syncthreads();
        {   // stage X0 = relu(e + asrc + adst) bf16, Hs = Hb[src]
            int so = soff_lds[srow], dofs = doff_lds[srow];
            const f32x4* ep = (const f32x4*)(ef + (size_t)(e0 + srow) * 128 + q * 32);
            const u16x8* ap = (const u16x8*)(Asrc + so + q * 32);
            const u16x8* dp = (const u16x8*)(Adst + dofs + q * 32);
            const u16x8* hp = (const u16x8*)(Hb + so + q * 32);
#pragma unroll
            for (int i = 0; i < 4; ++i) {
                u16x8 a8 = ap[i], d8 = dp[i], h8 = hp[i];
                f32x4 e_lo = ep[2 * i], e_hi = ep[2 * i + 1];
                unsigned short o[8];
#pragma unroll
                for (int j = 0; j < 8; ++j) {
                    float evv = (j < 4) ? e_lo[j] : e_hi[j - 4];
                    float v = evv + bf2f((unsigned short)a8[j]) + bf2f((unsigned short)d8[j]);
                    o[j] = f2bf(fmaxf(v, 0.f));
                }
                *(u16x8*)(X0 + srow * 136 + q * 32 + i * 8) = *(u16x8*)o;
                *(u16x8*)(Hs + srow * 136 + q * 32 + i * 8) = h8;
            }
        }
        __syncthreads();
        f32x4 acc[4][2];
        zero_acc(acc);
        gemm64(X0, wf1, acc, lane);
        __syncthreads();                       // all X0 reads done
        epi_lds(X1, acc, b1_0, b1_1, c0, rbase);
        __syncthreads();                       // X1 writes done
        zero_acc(acc);
        gemm64(X1, wf2, acc, lane);
        epi_lds(X0, acc, b2_0, b2_1, c0, rbase);   // X0 free since sync after L1
        __syncthreads();                       // X0 writes done
        zero_acc(acc);
        gemm64(X0, wf3, acc, lane);
        // m = Hb[src] * (acc + b3); scatter-add into agg[dst]
#pragma unroll
        for (int mt = 0; mt < 4; ++mt)
#pragma unroll
            for (int r = 0; r < 4; ++r) {
                int row = mt * 16 + rbase + r;
                int dofs = doff_lds[row];
                float h0 = bf2f(Hs[row * 136 + c0]);
                float h1 = bf2f(Hs[row * 136 + c0 + 16]);
                atomicAdd(agg + dofs + c0,      (acc[mt][0][r] + b3_0) * h0);
                atomicAdd(agg + dofs + c0 + 16, (acc[mt][1][r] + b3_1) * h1);
            }
    }
}

// ================= kernel 4: node output =================
__global__ __launch_bounds__(256, 2)
void k_nodeout(const unsigned short* __restrict__ Hb,
               const float* __restrict__ agg,
               const unsigned short* __restrict__ Wb,
               const float* __restrict__ bpd, const float* __restrict__ bpu,
               const float* __restrict__ bt1, const float* __restrict__ bt2,
               float* __restrict__ out) {
    __shared__ unsigned short Xh[64 * 136];
    __shared__ unsigned short Xa[64 * 136];
    int tid = threadIdx.x, lane = tid & 63, wv = tid >> 6;
    int n0 = blockIdx.x * 64;
    {
        int row = tid >> 2, q = tid & 3;
        int n = n0 + row;
        if (n < NN) {
            const u16x8* hp = (const u16x8*)(Hb + (size_t)n * 128 + q * 32);
#pragma unroll
            for (int i = 0; i < 4; ++i)
                *(u16x8*)(Xh + row * 136 + q * 32 + i * 8) = hp[i];
            const f32x4* gp = (const f32x4*)(agg + (size_t)n * 128 + q * 32);
#pragma unroll
            for (int i = 0; i < 4; ++i) {
                f32x4 lo = gp[2 * i], hi = gp[2 * i + 1];
                unsigned short tmp[8];
#pragma unroll
                for (int j = 0; j < 4; ++j) { tmp[j] = f2bf(lo[j]); tmp[4 + j] = f2bf(hi[j]); }
                *(u16x8*)(Xa + row * 136 + q * 32 + i * 8) = *(u16x8*)tmp;
            }
        } else {
            u16x8 z = {0, 0, 0, 0, 0, 0, 0, 0};
#pragma unroll
            for (int i = 0; i < 4; ++i) {
                *(u16x8*)(Xh + row * 136 + q * 32 + i * 8) = z;
                *(u16x8*)(Xa + row * 136 + q * 32 + i * 8) = z;
            }
        }
    }
    __syncthreads();
    bf16x8 wfa[4][2], wfb[4][2];
    load_wfrags(Wb + 5 * 16384, wv, lane, wfa);   // Wpd
    load_wfrags(Wb + 6 * 16384, wv, lane, wfb);   // Wpu
    int c0 = 32 * wv + (lane & 15);
    int rbase = (lane >> 4) * 4;
    f32x4 acc[4][2];
    zero_acc(acc);
    gemm64(Xh, wfa, acc, lane);
    gemm64(Xa, wfb, acc, lane);
    float bb0 = bpd[c0] + bpu[c0], bb1 = bpd[c0 + 16] + bpu[c0 + 16];
    __syncthreads();
    epi_lds(Xh, acc, bb0, bb1, c0, rbase);        // y1 = relu(...)
    __syncthreads();
    load_wfrags(Wb + 7 * 16384, wv, lane, wfa);   // Wth1
    zero_acc(acc);
    gemm64(Xh, wfa, acc, lane);
    float b10 = bt1[c0], b11 = bt1[c0 + 16];
    __syncthreads();
    epi_lds(Xa, acc, b10, b11, c0, rbase);        // y2 = relu(...)
    __syncthreads();
    load_wfrags(Wb + 8 * 16384, wv, lane, wfb);   // Wth2
    zero_acc(acc);
    gemm64(Xa, wfb, acc, lane);
    float b20 = bt2[c0], b21 = bt2[c0 + 16];
#pragma unroll
    for (int mt = 0; mt < 4; ++mt)
#pragma unroll
        for (int r = 0; r < 4; ++r) {
            int n = n0 + mt * 16 + rbase + r;
            if (n < NN) {
                out[(size_t)n * 128 + c0]      = acc[mt][0][r] + b20;
                out[(size_t)n * 128 + c0 + 16] = acc[mt][1][r] + b21;
            }
        }
}

extern "C" void kernel_launch(void* const* d_in, const int* in_sizes, int n_in,
                              void* d_out, int out_size, void* d_ws, size_t ws_size,
                              hipStream_t stream) {
    (void)in_sizes; (void)n_in; (void)out_size; (void)ws_size;
    const float* node_feat = (const float*)d_in[0];
    const float* edge_feat = (const float*)d_in[1];
    const int*   src  = (const int*)d_in[2];
    const int*   dst  = (const int*)d_in[3];
    const float* Wsrc = (const float*)d_in[4];  const float* bsrc = (const float*)d_in[5];
    const float* Wdst = (const float*)d_in[6];  const float* bdst = (const float*)d_in[7];
    const float* Wphi1 = (const float*)d_in[8]; const float* bphi1 = (const float*)d_in[9];
    const float* Wphi2 = (const float*)d_in[10];const float* bphi2 = (const float*)d_in[11];
    const float* Wphi3 = (const float*)d_in[12];const float* bphi3 = (const float*)d_in[13];
    const float* Wth1 = (const float*)d_in[14]; const float* bth1 = (const float*)d_in[15];
    const float* Wth2 = (const float*)d_in[16]; const float* bth2 = (const float*)d_in[17];
    const float* Wpd  = (const float*)d_in[18]; const float* bpd  = (const float*)d_in[19];
    const float* Wpu  = (const float*)d_in[20]; const float* bpu  = (const float*)d_in[21];

    // workspace layout (total ~61.3 MB)
    char* ws = (char*)d_ws;
    unsigned short* Wb   = (unsigned short*)ws;                          // 294912 B
    unsigned short* Asrc = (unsigned short*)(ws + 294912);               // 12.8 MB
    unsigned short* Adst = (unsigned short*)(ws + 294912 + 12800000);    // 12.8 MB
    unsigned short* Hb   = (unsigned short*)(ws + 294912 + 25600000);    // 12.8 MB
    float*          agg  = (float*)(ws + 294912 + 38400000);             // 25.6 MB

    hipMemsetAsync(agg, 0, (size_t)NN * 128 * 4, stream);

    k_wconv<<<36, 256, 0, stream>>>(Wsrc, Wdst, Wphi1, Wphi2, Wphi3,
                                    Wpd, Wpu, Wth1, Wth2, Wb);
    k_nodepre<<<782, 256, 0, stream>>>(node_feat, Wb, bsrc, bdst, Asrc, Adst, Hb);
    k_edge<<<1024, 256, 0, stream>>>(edge_feat, src, dst, Asrc, Adst, Hb, Wb,
                                     bphi1, bphi2, bphi3, agg);
    k_nodeout<<<782, 256, 0, stream>>>(Hb, agg, Wb, bpd, bpu, bth1, bth2, (float*)d_out);
}